// Round 1
// baseline (69.680 us; speedup 1.0000x reference)
//
#include <hip/hip_runtime.h>
#include <cstdint>

// Problem constants (from setup_inputs: logits/targets [16,1,512,512] f32)
#define BB 16
#define HH 512
#define WW 512
#define NPIX (BB*HH*WW)          // 4194304
#define NBLK (NPIX/256)          // 16384

// ---------------------------------------------------------------------------
// Kernel A: per-pixel column distance to nearest OPPOSITE-value pixel along H.
// At each pixel exactly one of d1_t, d1_nt is zero; the other equals the
// distance to the nearest opposite pixel in the column. Pack (d<<1)|t.
// Expanding search: first k (in either direction) with opposite value IS the
// minimum distance. Expected ~1-3 iterations for random p=0.5 data.
// ---------------------------------------------------------------------------
__global__ void colpass(const float* __restrict__ targets,
                        uint16_t* __restrict__ packed) {
    int idx = blockIdx.x * blockDim.x + threadIdx.x;
    if (idx >= NPIX) return;
    int i = (idx / WW) % HH;                 // row within image
    int tb = (targets[idx] > 0.5f) ? 1 : 0;

    int kmaxUp = i;
    int kmaxDn = HH - 1 - i;
    int kmax = kmaxUp > kmaxDn ? kmaxUp : kmaxDn;

    int d = 1023;  // acts as +inf: 1023^2 > max real dt2 (511^2+511^2)
    for (int k = 1; k <= kmax; ++k) {
        bool hit = false;
        if (k <= kmaxUp) {
            int tu = (targets[idx - k * WW] > 0.5f) ? 1 : 0;
            hit |= (tu != tb);
        }
        if (k <= kmaxDn) {
            int td = (targets[idx + k * WW] > 0.5f) ? 1 : 0;
            hit |= (td != tb);
        }
        if (hit) { d = k; break; }
    }
    packed[idx] = (uint16_t)((d << 1) | tb);
}

// ---------------------------------------------------------------------------
// Kernel B: exact pruned row transform + sigmoid + p*dt, block partial sums.
// dt2(j) = min_j' d1_S(j')^2 + (j-j')^2 where S = opposite set of t(j):
//   d1_S(j') = (t(j')==t(j)) ? d(j') : 0.
// Expand k outward; stop when k^2 >= current min (exact pruning).
// ---------------------------------------------------------------------------
__global__ void rowpass(const uint16_t* __restrict__ packed,
                        const float* __restrict__ logits,
                        float* __restrict__ partial) {
    int idx = blockIdx.x * blockDim.x + threadIdx.x;
    int j = idx & (WW - 1);
    int rowbase = idx - j;

    unsigned pk = packed[idx];
    int tb = (int)(pk & 1u);
    int d  = (int)(pk >> 1);
    int m  = d * d;

    int kmaxL = j;
    int kmaxR = WW - 1 - j;
    int kmax  = kmaxL > kmaxR ? kmaxL : kmaxR;

    for (int k = 1; k <= kmax && k * k < m; ++k) {
        int k2 = k * k;
        if (k <= kmaxL) {
            unsigned p2 = packed[rowbase + j - k];
            int dd = ((int)(p2 & 1u) == tb) ? (int)(p2 >> 1) : 0;
            int c = dd * dd + k2;
            m = c < m ? c : m;
        }
        if (k <= kmaxR) {
            unsigned p2 = packed[rowbase + j + k];
            int dd = ((int)(p2 & 1u) == tb) ? (int)(p2 >> 1) : 0;
            int c = dd * dd + k2;
            m = c < m ? c : m;
        }
    }

    float dt = sqrtf((float)m);

    float x = logits[idx];
    float p = 1.0f / (1.0f + expf(-x));
    const float lo = 1e-7f;
    const float hi = (float)(1.0 - 1e-7);
    p = fminf(fmaxf(p, lo), hi);

    float v = p * dt;

    // block reduction (256 threads = 4 waves of 64)
    #pragma unroll
    for (int off = 32; off > 0; off >>= 1)
        v += __shfl_down(v, off);

    __shared__ float sw[4];
    int lane = threadIdx.x & 63;
    int wid  = threadIdx.x >> 6;
    if (lane == 0) sw[wid] = v;
    __syncthreads();
    if (threadIdx.x == 0)
        partial[blockIdx.x] = sw[0] + sw[1] + sw[2] + sw[3];
}

// ---------------------------------------------------------------------------
// Kernel C: deterministic final reduction of NBLK partials -> mean
// ---------------------------------------------------------------------------
__global__ void finalreduce(const float* __restrict__ partial,
                            float* __restrict__ out) {
    float v = 0.0f;
    for (int i = threadIdx.x; i < NBLK; i += 256)
        v += partial[i];

    #pragma unroll
    for (int off = 32; off > 0; off >>= 1)
        v += __shfl_down(v, off);

    __shared__ float sw[4];
    int lane = threadIdx.x & 63;
    int wid  = threadIdx.x >> 6;
    if (lane == 0) sw[wid] = v;
    __syncthreads();
    if (threadIdx.x == 0)
        out[0] = (sw[0] + sw[1] + sw[2] + sw[3]) * (1.0f / (float)NPIX);
}

extern "C" void kernel_launch(void* const* d_in, const int* in_sizes, int n_in,
                              void* d_out, int out_size, void* d_ws, size_t ws_size,
                              hipStream_t stream) {
    const float* logits  = (const float*)d_in[0];
    const float* targets = (const float*)d_in[1];
    float* out = (float*)d_out;

    // workspace layout: [ packed uint16 NPIX | partial float NBLK ]
    uint16_t* packed = (uint16_t*)d_ws;
    float* partial = (float*)((char*)d_ws + (size_t)NPIX * sizeof(uint16_t));

    colpass<<<NBLK, 256, 0, stream>>>(targets, packed);
    rowpass<<<NBLK, 256, 0, stream>>>(packed, logits, partial);
    finalreduce<<<1, 256, 0, stream>>>(partial, out);
}

// Round 3
// 47.256 us; speedup vs baseline: 1.4745x; 1.4745x over previous
//
#include <hip/hip_runtime.h>
#include <cstdint>

// Problem constants (from setup_inputs: logits/targets [16,1,512,512] f32)
#define BB 16
#define HH 512
#define WW 512
#define NPIX (BB*HH*WW)          // 4194304
#define NROWS (BB*HH)            // 8192 (one block per image row)

// ---------------------------------------------------------------------------
// Fused kernel: one block per row (b,i), 512 threads = one pixel each.
//  Phase 1: column distance to nearest OPPOSITE pixel (exact; expanding
//           search, branchless-unrolled k=1..4, rare tail loop).
//  Phase 2: packed (d<<1)|t into LDS; exact pruned row transform
//           dt2(j) = min_k  d1_opp(j+-k)^2 + k^2, stop when k^2 >= min.
//  Phase 3: p = clip(sigmoid(logit)); block-reduce sum of p*sqrt(dt2).
// All distance math is integer-exact (values < 2^21, exact in f32).
// ---------------------------------------------------------------------------
__global__ __launch_bounds__(512) void fused_row(
        const float* __restrict__ targets,
        const float* __restrict__ logits,
        float* __restrict__ partial) {
    const int row = blockIdx.x;            // b*HH + i
    const int i   = row & (HH - 1);
    const int j   = threadIdx.x;
    const int idx = row * WW + j;

    __shared__ uint32_t pk_s[WW];
    __shared__ float    sw[8];

    const int tb = (targets[idx] > 0.5f) ? 1 : 0;
    const int kmaxUp = i;
    const int kmaxDn = HH - 1 - i;

    // ---- Phase 1: column search ----
    int d = 1023;   // +inf surrogate: 1023^2 > max real dt2 (511^2+511^2)
    #pragma unroll
    for (int k = 1; k <= 4; ++k) {
        const bool up_ok = (k <= kmaxUp);
        const bool dn_ok = (k <= kmaxDn);
        const int iu = up_ok ? (idx - k * WW) : idx;
        const int id = dn_ok ? (idx + k * WW) : idx;
        const int tu = (targets[iu] > 0.5f) ? 1 : 0;
        const int td = (targets[id] > 0.5f) ? 1 : 0;
        const bool hit = (up_ok && (tu != tb)) || (dn_ok && (td != tb));
        d = min(d, hit ? k : 1023);
    }
    if (d == 1023) {               // rare (~22% of waves have such a lane)
        const int kmax = max(kmaxUp, kmaxDn);
        for (int k = 5; k <= kmax; ++k) {
            bool hit = false;
            if (k <= kmaxUp) hit |= (((targets[idx - k * WW] > 0.5f) ? 1 : 0) != tb);
            if (k <= kmaxDn) hit |= (((targets[idx + k * WW] > 0.5f) ? 1 : 0) != tb);
            if (hit) { d = k; break; }
        }
    }

    pk_s[j] = (uint32_t)((d << 1) | tb);
    __syncthreads();

    // ---- Phase 2: row transform (exact pruned) ----
    int m = d * d;
    #pragma unroll
    for (int k = 1; k <= 2; ++k) {
        const int jl = j - k, jr = j + k;
        const uint32_t pl = pk_s[jl >= 0 ? jl : 0];
        const uint32_t pr = pk_s[jr < WW ? jr : (WW - 1)];
        const int dl = ((int)(pl & 1u) == tb) ? (int)(pl >> 1) : 0;
        const int dr = ((int)(pr & 1u) == tb) ? (int)(pr >> 1) : 0;
        const int cl = (jl >= 0) ? (dl * dl + k * k) : 0x7fffffff;
        const int cr = (jr < WW) ? (dr * dr + k * k) : 0x7fffffff;
        m = min(m, min(cl, cr));
    }
    {
        const int kmaxRow = max(j, WW - 1 - j);
        for (int k = 3; k <= kmaxRow && k * k < m; ++k) {
            const int k2 = k * k;
            if (k <= j) {
                const uint32_t p2 = pk_s[j - k];
                const int dd = ((int)(p2 & 1u) == tb) ? (int)(p2 >> 1) : 0;
                const int c = dd * dd + k2;
                m = c < m ? c : m;
            }
            if (k <= WW - 1 - j) {
                const uint32_t p2 = pk_s[j + k];
                const int dd = ((int)(p2 & 1u) == tb) ? (int)(p2 >> 1) : 0;
                const int c = dd * dd + k2;
                m = c < m ? c : m;
            }
        }
    }

    const float dt = sqrtf((float)m);

    // ---- Phase 3: loss term + block reduction ----
    const float x = logits[idx];
    float p = 1.0f / (1.0f + __expf(-x));
    p = fminf(fmaxf(p, 1e-7f), (float)(1.0 - 1e-7));
    float v = p * dt;

    #pragma unroll
    for (int off = 32; off > 0; off >>= 1)
        v += __shfl_down(v, off);

    const int lane = threadIdx.x & 63;
    const int wid  = threadIdx.x >> 6;
    if (lane == 0) sw[wid] = v;
    __syncthreads();
    if (threadIdx.x == 0) {
        float s = 0.0f;
        #pragma unroll
        for (int w = 0; w < 8; ++w) s += sw[w];
        partial[blockIdx.x] = s;
    }
}

// ---------------------------------------------------------------------------
// Deterministic final reduction of NROWS partials -> mean
// ---------------------------------------------------------------------------
__global__ __launch_bounds__(512) void finalreduce(
        const float* __restrict__ partial,
        float* __restrict__ out) {
    float v = 0.0f;
    for (int i = threadIdx.x; i < NROWS; i += 512)
        v += partial[i];

    #pragma unroll
    for (int off = 32; off > 0; off >>= 1)
        v += __shfl_down(v, off);

    __shared__ float sw[8];
    const int lane = threadIdx.x & 63;
    const int wid  = threadIdx.x >> 6;
    if (lane == 0) sw[wid] = v;
    __syncthreads();
    if (threadIdx.x == 0) {
        float s = 0.0f;
        #pragma unroll
        for (int w = 0; w < 8; ++w) s += sw[w];
        out[0] = s * (1.0f / (float)NPIX);
    }
}

extern "C" void kernel_launch(void* const* d_in, const int* in_sizes, int n_in,
                              void* d_out, int out_size, void* d_ws, size_t ws_size,
                              hipStream_t stream) {
    const float* logits  = (const float*)d_in[0];
    const float* targets = (const float*)d_in[1];
    float* out = (float*)d_out;

    float* partial = (float*)d_ws;   // NROWS floats

    fused_row<<<NROWS, 512, 0, stream>>>(targets, logits, partial);
    finalreduce<<<1, 512, 0, stream>>>(partial, out);
}

// Round 4
// 34.424 us; speedup vs baseline: 2.0242x; 1.3728x over previous
//
#include <hip/hip_runtime.h>
#include <cstdint>

// Problem constants (from setup_inputs: logits/targets [16,1,512,512] f32)
#define BB 16
#define HH 512
#define WW 512
#define NPIX (BB*HH*WW)          // 4194304
#define NROWS (BB*HH)            // 8192 (one block per image row)
#define NXCD 8
#define CHUNK (NROWS/NXCD)       // 1024

// ---------------------------------------------------------------------------
// Fused kernel: one block per row (b,i), 512 threads = one pixel each.
//  Phase 1: column distance to nearest OPPOSITE pixel (exact; expanding
//           search, branchless-unrolled k=1..6, rare tail loop ~1.5%/wave).
//  Phase 2: packed (d<<1)|t into LDS; exact pruned row transform
//           dt2(j) = min_k  d1_opp(j+-k)^2 + k^2, stop when k^2 >= min.
//  Phase 3: p = clip(sigmoid(logit)); block-reduce sum of p*sqrt(dt2).
// All distance math is integer-exact (values < 2^21, exact in f32).
// Row index is XCD-swizzled: each XCD gets a contiguous 1024-row chunk so
// the +-6-row reuse window of `targets` stays within one per-XCD L2.
// ---------------------------------------------------------------------------
__global__ __launch_bounds__(512) void fused_row(
        const float* __restrict__ targets,
        const float* __restrict__ logits,
        float* __restrict__ partial) {
    const int bid = blockIdx.x;
    const int row = (bid & (NXCD - 1)) * CHUNK + (bid >> 3);  // bijective swizzle
    const int i   = row & (HH - 1);
    const int j   = threadIdx.x;
    const int idx = row * WW + j;

    __shared__ uint32_t pk_s[WW];
    __shared__ float    sw[8];

    // issue logits load early; overlaps the column search
    const float x = logits[idx];

    const int tb = (targets[idx] > 0.5f) ? 1 : 0;
    const int kmaxUp = i;
    const int kmaxDn = HH - 1 - i;

    // ---- Phase 1: column search (branchless unroll k=1..6) ----
    int d = 1023;   // +inf surrogate: 1023^2 > max real dt2 (511^2+511^2)
    #pragma unroll
    for (int k = 1; k <= 6; ++k) {
        const bool up_ok = (k <= kmaxUp);
        const bool dn_ok = (k <= kmaxDn);
        const int iu = up_ok ? (idx - k * WW) : idx;
        const int id = dn_ok ? (idx + k * WW) : idx;
        const int tu = (targets[iu] > 0.5f) ? 1 : 0;
        const int td = (targets[id] > 0.5f) ? 1 : 0;
        const bool hit = (up_ok && (tu != tb)) || (dn_ok && (td != tb));
        d = min(d, hit ? k : 1023);
    }
    if (d == 1023) {               // rare: ~1.5% of waves have such a lane
        const int kmax = max(kmaxUp, kmaxDn);
        for (int k = 7; k <= kmax; ++k) {
            bool hit = false;
            if (k <= kmaxUp) hit |= (((targets[idx - k * WW] > 0.5f) ? 1 : 0) != tb);
            if (k <= kmaxDn) hit |= (((targets[idx + k * WW] > 0.5f) ? 1 : 0) != tb);
            if (hit) { d = k; break; }
        }
    }

    pk_s[j] = (uint32_t)((d << 1) | tb);
    __syncthreads();

    // ---- Phase 2: row transform (exact pruned) ----
    int m = d * d;
    #pragma unroll
    for (int k = 1; k <= 2; ++k) {
        const int jl = j - k, jr = j + k;
        const uint32_t pl = pk_s[jl >= 0 ? jl : 0];
        const uint32_t pr = pk_s[jr < WW ? jr : (WW - 1)];
        const int dl = ((int)(pl & 1u) == tb) ? (int)(pl >> 1) : 0;
        const int dr = ((int)(pr & 1u) == tb) ? (int)(pr >> 1) : 0;
        const int cl = (jl >= 0) ? (dl * dl + k * k) : 0x7fffffff;
        const int cr = (jr < WW) ? (dr * dr + k * k) : 0x7fffffff;
        m = min(m, min(cl, cr));
    }
    {
        const int kmaxRow = max(j, WW - 1 - j);
        for (int k = 3; k <= kmaxRow && k * k < m; ++k) {
            const int k2 = k * k;
            if (k <= j) {
                const uint32_t p2 = pk_s[j - k];
                const int dd = ((int)(p2 & 1u) == tb) ? (int)(p2 >> 1) : 0;
                const int c = dd * dd + k2;
                m = c < m ? c : m;
            }
            if (k <= WW - 1 - j) {
                const uint32_t p2 = pk_s[j + k];
                const int dd = ((int)(p2 & 1u) == tb) ? (int)(p2 >> 1) : 0;
                const int c = dd * dd + k2;
                m = c < m ? c : m;
            }
        }
    }

    const float dt = sqrtf((float)m);

    // ---- Phase 3: loss term + block reduction ----
    float p = 1.0f / (1.0f + __expf(-x));
    p = fminf(fmaxf(p, 1e-7f), (float)(1.0 - 1e-7));
    float v = p * dt;

    #pragma unroll
    for (int off = 32; off > 0; off >>= 1)
        v += __shfl_down(v, off);

    const int lane = threadIdx.x & 63;
    const int wid  = threadIdx.x >> 6;
    if (lane == 0) sw[wid] = v;
    __syncthreads();
    if (threadIdx.x == 0) {
        float s = 0.0f;
        #pragma unroll
        for (int w = 0; w < 8; ++w) s += sw[w];
        partial[row] = s;
    }
}

// ---------------------------------------------------------------------------
// Deterministic final reduction of NROWS partials -> mean
// ---------------------------------------------------------------------------
__global__ __launch_bounds__(512) void finalreduce(
        const float* __restrict__ partial,
        float* __restrict__ out) {
    float v = 0.0f;
    for (int i = threadIdx.x; i < NROWS; i += 512)
        v += partial[i];

    #pragma unroll
    for (int off = 32; off > 0; off >>= 1)
        v += __shfl_down(v, off);

    __shared__ float sw[8];
    const int lane = threadIdx.x & 63;
    const int wid  = threadIdx.x >> 6;
    if (lane == 0) sw[wid] = v;
    __syncthreads();
    if (threadIdx.x == 0) {
        float s = 0.0f;
        #pragma unroll
        for (int w = 0; w < 8; ++w) s += sw[w];
        out[0] = s * (1.0f / (float)NPIX);
    }
}

extern "C" void kernel_launch(void* const* d_in, const int* in_sizes, int n_in,
                              void* d_out, int out_size, void* d_ws, size_t ws_size,
                              hipStream_t stream) {
    const float* logits  = (const float*)d_in[0];
    const float* targets = (const float*)d_in[1];
    float* out = (float*)d_out;

    float* partial = (float*)d_ws;   // NROWS floats

    fused_row<<<NROWS, 512, 0, stream>>>(targets, logits, partial);
    finalreduce<<<1, 512, 0, stream>>>(partial, out);
}

// Round 6
// 28.125 us; speedup vs baseline: 2.4775x; 1.2240x over previous
//
#include <hip/hip_runtime.h>
#include <cstdint>

// Problem constants (from setup_inputs: logits/targets [16,1,512,512] f32)
#define BB 16
#define HH 512
#define WW 512
#define NPIX (BB*HH*WW)          // 4194304
#define NROWS (BB*HH)            // 8192 (one block per image row)
#define WR (HH/32)               // 16 word-rows per image
#define NWORDS (BB*WR*WW)        // 131072 u32 = 512 KB
#define NXCD 8
#define CHUNK (NROWS/NXCD)       // 1024

// ---------------------------------------------------------------------------
// Kernel 0: vertical bit-pack of targets.
// vmask[b][w][j] bit r = (targets[b][32w+r][j] > 0.5).  512 KB total.
// ---------------------------------------------------------------------------
__global__ __launch_bounds__(256) void packbits(const float* __restrict__ targets,
                                                uint32_t* __restrict__ vmask) {
    const int flat = blockIdx.x * 256 + threadIdx.x;   // b*8192 + w*512 + j
    const int j = flat & (WW - 1);
    const int w = (flat >> 9) & (WR - 1);
    const int b = flat >> 13;
    const float* base = targets + ((size_t)b * HH + (size_t)w * 32) * WW + j;
    uint32_t word = 0;
    #pragma unroll
    for (int r = 0; r < 32; ++r)
        word |= (base[r * WW] > 0.5f ? 1u : 0u) << r;
    vmask[flat] = word;
}

// ---------------------------------------------------------------------------
// Fused kernel: one block per image row, 512 threads = one pixel each.
//  Phase 1: column distance to nearest OPPOSITE pixel via the bitmask:
//           3 u32 loads + ffs/clz on two 64-bit windows (covers +-32 rows
//           minimum); exact word-scan fallback beyond (P ~ 2^-32, never on
//           random data, needed for exactness).
//  Phase 2: packed (d<<1)|t into LDS; exact pruned row transform.
//  Phase 3: p = clip(sigmoid(logit)); block-reduce sum of p*sqrt(dt2).
// All distance math integer-exact. XCD swizzle keeps row locality per L2.
// ---------------------------------------------------------------------------
__global__ __launch_bounds__(512) void fused_row(
        const uint32_t* __restrict__ vmask,
        const float* __restrict__ logits,
        float* __restrict__ partial) {
    const int bid = blockIdx.x;
    const int row = (bid & (NXCD - 1)) * CHUNK + (bid >> 3);  // bijective swizzle
    const int b   = row >> 9;          // image
    const int i   = row & (HH - 1);    // row within image
    const int j   = threadIdx.x;
    const int idx = row * WW + j;
    const int w   = i >> 5;
    const int p   = i & 31;

    __shared__ uint32_t pk_s[WW];
    __shared__ float    sw[8];

    const uint32_t* vm = vmask + (size_t)b * WR * WW;  // this image's mask

    // issue logits load early; overlaps phase 1
    const float x = logits[idx];

    const uint32_t Wself = vm[w * WW + j];
    const int      t     = (int)((Wself >> p) & 1u);
    const uint32_t tm    = t ? 0xFFFFFFFFu : 0u;

    const uint32_t Xs = Wself ^ tm;                                  // 1 = opposite
    const uint32_t Xu = (w > 0)      ? (vm[(w - 1) * WW + j] ^ tm) : 0u;
    const uint32_t Xd = (w < WR - 1) ? (vm[(w + 1) * WW + j] ^ tm) : 0u;

    // down window: bit q = row i+1+q  (covers rows i+1 .. 32w+63)
    const uint64_t Zd = ((uint64_t)Xs >> (p + 1)) | ((uint64_t)Xd << (31 - p));
    // up window: bit 63 = row i-1, descending (covers rows 32w-32 .. i-1)
    const uint64_t Zu = (((uint64_t)Xs << 32) | (uint64_t)Xu) << (32 - p);

    int dd, du;
    if (Zd) {
        dd = __ffsll((unsigned long long)Zd);          // 1-based == distance
    } else {                                           // essentially never
        dd = 1023;
        for (int ww = w + 2; ww < WR; ++ww) {
            const uint32_t Xw = vm[ww * WW + j] ^ tm;
            if (Xw) { dd = 32 * ww + (__ffs(Xw) - 1) - i; break; }
        }
    }
    if (Zu) {
        du = __clzll((long long)Zu) + 1;
    } else {                                           // essentially never
        du = 1023;
        for (int ww = w - 2; ww >= 0; --ww) {
            const uint32_t Xw = vm[ww * WW + j] ^ tm;
            if (Xw) { du = i - (32 * ww + 31 - __clz((int)Xw)); break; }
        }
    }
    const int d = min(min(dd, du), 1023);

    pk_s[j] = (uint32_t)((d << 1) | t);
    __syncthreads();

    // ---- Phase 2: row transform (exact pruned) ----
    int m = d * d;
    #pragma unroll
    for (int k = 1; k <= 2; ++k) {
        const int jl = j - k, jr = j + k;
        const uint32_t pl = pk_s[jl >= 0 ? jl : 0];
        const uint32_t pr = pk_s[jr < WW ? jr : (WW - 1)];
        const int dl = ((int)(pl & 1u) == t) ? (int)(pl >> 1) : 0;
        const int dr = ((int)(pr & 1u) == t) ? (int)(pr >> 1) : 0;
        const int cl = (jl >= 0) ? (dl * dl + k * k) : 0x7fffffff;
        const int cr = (jr < WW) ? (dr * dr + k * k) : 0x7fffffff;
        m = min(m, min(cl, cr));
    }
    {
        const int kmaxRow = max(j, WW - 1 - j);
        for (int k = 3; k <= kmaxRow && k * k < m; ++k) {
            const int k2 = k * k;
            if (k <= j) {
                const uint32_t p2 = pk_s[j - k];
                const int ddx = ((int)(p2 & 1u) == t) ? (int)(p2 >> 1) : 0;
                const int c = ddx * ddx + k2;
                m = c < m ? c : m;
            }
            if (k <= WW - 1 - j) {
                const uint32_t p2 = pk_s[j + k];
                const int ddx = ((int)(p2 & 1u) == t) ? (int)(p2 >> 1) : 0;
                const int c = ddx * ddx + k2;
                m = c < m ? c : m;
            }
        }
    }

    const float dt = sqrtf((float)m);

    // ---- Phase 3: loss term + block reduction ----
    float pr = 1.0f / (1.0f + __expf(-x));
    pr = fminf(fmaxf(pr, 1e-7f), (float)(1.0 - 1e-7));
    float v = pr * dt;

    #pragma unroll
    for (int off = 32; off > 0; off >>= 1)
        v += __shfl_down(v, off);

    const int lane = threadIdx.x & 63;
    const int wid  = threadIdx.x >> 6;
    if (lane == 0) sw[wid] = v;
    __syncthreads();
    if (threadIdx.x == 0) {
        float s = 0.0f;
        #pragma unroll
        for (int ww = 0; ww < 8; ++ww) s += sw[ww];
        partial[row] = s;
    }
}

// ---------------------------------------------------------------------------
// Deterministic final reduction of NROWS partials -> mean
// ---------------------------------------------------------------------------
__global__ __launch_bounds__(512) void finalreduce(
        const float* __restrict__ partial,
        float* __restrict__ out) {
    const float4* p4 = (const float4*)partial;
    float v = 0.0f;
    #pragma unroll
    for (int it = 0; it < NROWS / 4 / 512; ++it) {
        const float4 q = p4[it * 512 + threadIdx.x];
        v += (q.x + q.y) + (q.z + q.w);
    }

    #pragma unroll
    for (int off = 32; off > 0; off >>= 1)
        v += __shfl_down(v, off);

    __shared__ float sw[8];
    const int lane = threadIdx.x & 63;
    const int wid  = threadIdx.x >> 6;
    if (lane == 0) sw[wid] = v;
    __syncthreads();
    if (threadIdx.x == 0) {
        float s = 0.0f;
        #pragma unroll
        for (int ww = 0; ww < 8; ++ww) s += sw[ww];
        out[0] = s * (1.0f / (float)NPIX);
    }
}

extern "C" void kernel_launch(void* const* d_in, const int* in_sizes, int n_in,
                              void* d_out, int out_size, void* d_ws, size_t ws_size,
                              hipStream_t stream) {
    const float* logits  = (const float*)d_in[0];
    const float* targets = (const float*)d_in[1];
    float* out = (float*)d_out;

    // workspace layout: [ vmask u32 NWORDS (512KB) | partial float NROWS (32KB) ]
    uint32_t* vmask = (uint32_t*)d_ws;
    float* partial  = (float*)((char*)d_ws + (size_t)NWORDS * sizeof(uint32_t));

    packbits<<<NWORDS / 256, 256, 0, stream>>>(targets, vmask);
    fused_row<<<NROWS, 512, 0, stream>>>(vmask, logits, partial);
    finalreduce<<<1, 512, 0, stream>>>(partial, out);
}